// Round 1
// baseline (587.109 us; speedup 1.0000x reference)
//
#include <hip/hip_runtime.h>
#include <hip/hip_bf16.h>

#define N_NODES 50000
#define N_EDGES 800000
#define NFEAT   256
#define NHID    64
#define HEADS   4
#define NCLASS  16
#define NEG_SLOPE 0.2f

// ---------------- CSR build ----------------
__global__ void hist_kernel(const int* __restrict__ dst, int* __restrict__ cnt) {
    int e = blockIdx.x * blockDim.x + threadIdx.x;
    if (e < N_EDGES) atomicAdd(&cnt[dst[e]], 1);
}

// single block, 1024 threads: chunked Hillis-Steele exclusive scan
__global__ void scan_kernel(const int* __restrict__ cnt, int* __restrict__ row_ptr) {
    __shared__ int s[1024];
    __shared__ int carry_s;
    int t = threadIdx.x;
    if (t == 0) carry_s = 0;
    __syncthreads();
    for (int base = 0; base < N_NODES; base += 1024) {
        int idx = base + t;
        int v = (idx < N_NODES) ? cnt[idx] : 0;
        s[t] = v;
        __syncthreads();
        for (int off = 1; off < 1024; off <<= 1) {
            int x = (t >= off) ? s[t - off] : 0;
            __syncthreads();
            s[t] += x;
            __syncthreads();
        }
        int incl = s[t];
        if (idx < N_NODES) row_ptr[idx] = carry_s + (incl - v);
        __syncthreads();
        if (t == 0) carry_s += s[1023];
        __syncthreads();
    }
    if (t == 0) row_ptr[N_NODES] = carry_s;
}

__global__ void scatter_kernel(const int* __restrict__ src, const int* __restrict__ dst,
                               const int* __restrict__ row_ptr, int* __restrict__ fill,
                               int* __restrict__ csr_src) {
    int e = blockIdx.x * blockDim.x + threadIdx.x;
    if (e < N_EDGES) {
        int d = dst[e];
        int pos = row_ptr[d] + atomicAdd(&fill[d], 1);
        csr_src[pos] = src[e];
    }
}

// ---------------- GEMM1: feat1 = x @ W1  (fp32, 64x64 tile, 4x4 per thread) ----------------
__global__ __launch_bounds__(256) void gemm1_kernel(const float* __restrict__ A,
                                                    const float* __restrict__ B,
                                                    float* __restrict__ C) {
    __shared__ float As[16][68];
    __shared__ float Bs[16][68];
    int t  = threadIdx.x;
    int m0 = blockIdx.x * 64;
    int n0 = blockIdx.y * 64;
    int ty = t >> 4, tx = t & 15;
    int ty4 = ty * 4, tx4 = tx * 4;
    float acc[4][4];
#pragma unroll
    for (int i = 0; i < 4; ++i)
#pragma unroll
        for (int j = 0; j < 4; ++j) acc[i][j] = 0.f;

    int rA = t >> 2, kqA = (t & 3) * 4;   // A tile load: 64 rows x 16 k
    int rB = t >> 4, cB  = (t & 15) * 4;  // B tile load: 16 k x 64 n

    for (int k0 = 0; k0 < NFEAT; k0 += 16) {
        float4 av = make_float4(0.f, 0.f, 0.f, 0.f);
        int rowA = m0 + rA;
        if (rowA < N_NODES) av = *(const float4*)&A[rowA * NFEAT + k0 + kqA];
        As[kqA + 0][rA] = av.x;
        As[kqA + 1][rA] = av.y;
        As[kqA + 2][rA] = av.z;
        As[kqA + 3][rA] = av.w;
        *(float4*)&Bs[rB][cB] = *(const float4*)&B[(k0 + rB) * 256 + n0 + cB];
        __syncthreads();
#pragma unroll
        for (int k = 0; k < 16; ++k) {
            float4 a4 = *(const float4*)&As[k][ty4];
            float4 b4 = *(const float4*)&Bs[k][tx4];
            float a[4] = {a4.x, a4.y, a4.z, a4.w};
            float b[4] = {b4.x, b4.y, b4.z, b4.w};
#pragma unroll
            for (int i = 0; i < 4; ++i)
#pragma unroll
                for (int j = 0; j < 4; ++j) acc[i][j] += a[i] * b[j];
        }
        __syncthreads();
    }
#pragma unroll
    for (int i = 0; i < 4; ++i) {
        int row = m0 + ty4 + i;
        if (row < N_NODES) {
            float4 v = make_float4(acc[i][0], acc[i][1], acc[i][2], acc[i][3]);
            *(float4*)&C[row * 256 + n0 + tx4] = v;
        }
    }
}

// ---------------- el1/er1: per-node per-head attention dots ----------------
__global__ void lel1_kernel(const float* __restrict__ feat1, const float* __restrict__ al,
                            const float* __restrict__ ar, float* __restrict__ el,
                            float* __restrict__ er) {
    int wave = threadIdx.x >> 6, lane = threadIdx.x & 63;
    int n = blockIdx.x * 4 + wave;
    if (n >= N_NODES) return;
    float4 f = *(const float4*)&feat1[n * 256 + lane * 4];
    float4 a = *(const float4*)&al[lane * 4];
    float4 r = *(const float4*)&ar[lane * 4];
    float pl = f.x * a.x + f.y * a.y + f.z * a.z + f.w * a.w;
    float pr = f.x * r.x + f.y * r.y + f.z * r.z + f.w * r.w;
#pragma unroll
    for (int off = 1; off < 16; off <<= 1) {
        pl += __shfl_xor(pl, off);
        pr += __shfl_xor(pr, off);
    }
    if ((lane & 15) == 0) {
        el[n * 4 + (lane >> 4)] = pl;
        er[n * 4 + (lane >> 4)] = pr;
    }
}

__device__ __forceinline__ float leaky(float x) { return x > 0.f ? x : NEG_SLOPE * x; }

// ---------------- layer-1 aggregation: one wave per dst node ----------------
__global__ void agg1_kernel(const float* __restrict__ feat1, const float* __restrict__ el,
                            const float* __restrict__ er, const int* __restrict__ row_ptr,
                            const int* __restrict__ csr_src, const float* __restrict__ b1,
                            float* __restrict__ h1) {
    int wave = threadIdx.x >> 6, lane = threadIdx.x & 63;
    int n = blockIdx.x * 4 + wave;
    if (n >= N_NODES) return;
    int start = row_ptr[n], end = row_ptr[n + 1];
    float4 er4 = *(const float4*)&er[n * 4];

    // pass 1: per-head max over incident edges
    float4 m = make_float4(-1e30f, -1e30f, -1e30f, -1e30f);
    for (int i = start + lane; i < end; i += 64) {
        int s = csr_src[i];
        float4 el4 = *(const float4*)&el[s * 4];
        m.x = fmaxf(m.x, leaky(el4.x + er4.x));
        m.y = fmaxf(m.y, leaky(el4.y + er4.y));
        m.z = fmaxf(m.z, leaky(el4.z + er4.z));
        m.w = fmaxf(m.w, leaky(el4.w + er4.w));
    }
#pragma unroll
    for (int off = 32; off; off >>= 1) {
        m.x = fmaxf(m.x, __shfl_xor(m.x, off));
        m.y = fmaxf(m.y, __shfl_xor(m.y, off));
        m.z = fmaxf(m.z, __shfl_xor(m.z, off));
        m.w = fmaxf(m.w, __shfl_xor(m.w, off));
    }
    int h = lane >> 4;
    float m_h  = (h == 0) ? m.x : (h == 1) ? m.y : (h == 2) ? m.z : m.w;
    float er_h = (h == 0) ? er4.x : (h == 1) ? er4.y : (h == 2) ? er4.z : er4.w;

    // pass 2: accumulate feat[src]*exp(e-m) and denom
    float4 acc = make_float4(0.f, 0.f, 0.f, 0.f);
    float denom = 0.f;
    for (int i = start; i < end; ++i) {
        int s = csr_src[i];
        float e = leaky(el[s * 4 + h] + er_h);
        float ex = __expf(e - m_h);
        denom += ex;
        float4 f = *(const float4*)&feat1[s * 256 + lane * 4];
        acc.x += f.x * ex;
        acc.y += f.y * ex;
        acc.z += f.z * ex;
        acc.w += f.w * ex;
    }
    float inv = (end > start) ? 1.f / denom : 0.f;
    float4 b4 = *(const float4*)&b1[lane * 4];
    float4 o;
    o.x = acc.x * inv + b4.x;
    o.y = acc.y * inv + b4.y;
    o.z = acc.z * inv + b4.z;
    o.w = acc.w * inv + b4.w;
    // ELU
    o.x = o.x > 0.f ? o.x : __expf(o.x) - 1.f;
    o.y = o.y > 0.f ? o.y : __expf(o.y) - 1.f;
    o.z = o.z > 0.f ? o.z : __expf(o.z) - 1.f;
    o.w = o.w > 0.f ? o.w : __expf(o.w) - 1.f;
    *(float4*)&h1[n * 256 + lane * 4] = o;
}

// ---------------- GEMM2: feat2 = h1 @ W2  (16 rows/block) ----------------
__global__ __launch_bounds__(256) void gemm2_kernel(const float* __restrict__ h1,
                                                    const float* __restrict__ W2,
                                                    float* __restrict__ feat2) {
    __shared__ float Ws[4096];
    __shared__ float As[16][264];
    int t = threadIdx.x;
    int row0 = blockIdx.x * 16;
#pragma unroll
    for (int i = 0; i < 16; ++i) Ws[t + i * 256] = W2[t + i * 256];
    int r = t >> 4, kb = (t & 15) * 16;
    int row = row0 + r;
    if (row < N_NODES) {
#pragma unroll
        for (int j = 0; j < 16; j += 4)
            *(float4*)&As[r][kb + j] = *(const float4*)&h1[row * 256 + kb + j];
    } else {
#pragma unroll
        for (int j = 0; j < 16; j += 4)
            *(float4*)&As[r][kb + j] = make_float4(0.f, 0.f, 0.f, 0.f);
    }
    __syncthreads();
    int c = t & 15;
    float acc = 0.f;
#pragma unroll 8
    for (int k = 0; k < 256; ++k) acc += As[r][k] * Ws[k * 16 + c];
    if (row < N_NODES) feat2[row * 16 + c] = acc;
}

// ---------------- el2/er2 ----------------
__global__ void lel2_kernel(const float* __restrict__ feat2, const float* __restrict__ al2,
                            const float* __restrict__ ar2, float* __restrict__ el2,
                            float* __restrict__ er2) {
    int n = blockIdx.x * blockDim.x + threadIdx.x;
    if (n >= N_NODES) return;
    float sl = 0.f, sr = 0.f;
#pragma unroll
    for (int c = 0; c < 16; ++c) {
        float f = feat2[n * 16 + c];
        sl += f * al2[c];
        sr += f * ar2[c];
    }
    el2[n] = sl;
    er2[n] = sr;
}

// ---------------- layer-2 aggregation + log_softmax ----------------
__global__ void agg2_kernel(const float* __restrict__ feat2, const float* __restrict__ el2,
                            const float* __restrict__ er2, const int* __restrict__ row_ptr,
                            const int* __restrict__ csr_src, const float* __restrict__ b2,
                            float* __restrict__ out) {
    int wave = threadIdx.x >> 6, lane = threadIdx.x & 63;
    int n = blockIdx.x * 4 + wave;
    if (n >= N_NODES) return;
    int start = row_ptr[n], end = row_ptr[n + 1];
    float ern = er2[n];
    float m = -1e30f;
    for (int i = start + lane; i < end; i += 64) {
        int s = csr_src[i];
        m = fmaxf(m, leaky(el2[s] + ern));
    }
#pragma unroll
    for (int off = 32; off; off >>= 1) m = fmaxf(m, __shfl_xor(m, off));
    int c = lane & 15;
    float acc = 0.f, denom = 0.f;
    for (int i = start; i < end; ++i) {
        int s = csr_src[i];
        float e = leaky(el2[s] + ern);
        float ex = __expf(e - m);
        denom += ex;
        acc += feat2[s * 16 + c] * ex;
    }
    float v = ((end > start) ? acc / denom : 0.f) + b2[c];
    // log_softmax over the 16 classes (within 16-lane group; all 4 groups redundant)
    float mx = v;
#pragma unroll
    for (int off = 1; off < 16; off <<= 1) mx = fmaxf(mx, __shfl_xor(mx, off));
    float ex2 = __expf(v - mx);
    float s2 = ex2;
#pragma unroll
    for (int off = 1; off < 16; off <<= 1) s2 += __shfl_xor(s2, off);
    float res = v - mx - logf(s2);
    if (lane < 16) out[n * 16 + lane] = res;
}

// ---------------- launch ----------------
extern "C" void kernel_launch(void* const* d_in, const int* in_sizes, int n_in,
                              void* d_out, int out_size, void* d_ws, size_t ws_size,
                              hipStream_t stream) {
    const float* x   = (const float*)d_in[0];
    const int*   src = (const int*)d_in[1];
    const int*   dst = (const int*)d_in[2];
    const float* W1  = (const float*)d_in[3];
    const float* al1 = (const float*)d_in[4];
    const float* ar1 = (const float*)d_in[5];
    const float* b1  = (const float*)d_in[6];
    const float* W2  = (const float*)d_in[7];
    const float* al2 = (const float*)d_in[8];
    const float* ar2 = (const float*)d_in[9];
    const float* b2  = (const float*)d_in[10];
    float* out = (float*)d_out;

    char* ws = (char*)d_ws;
    size_t off = 0;
    auto alloc = [&](size_t bytes) -> void* {
        void* p = ws + off;
        off += (bytes + 255) & ~(size_t)255;
        return p;
    };
    float* feat1   = (float*)alloc((size_t)N_NODES * 256 * 4);
    float* h1      = (float*)alloc((size_t)N_NODES * 256 * 4);
    float* feat2   = (float*)alloc((size_t)N_NODES * 16 * 4);
    float* el1     = (float*)alloc((size_t)N_NODES * 4 * 4);
    float* er1     = (float*)alloc((size_t)N_NODES * 4 * 4);
    float* el2     = (float*)alloc((size_t)N_NODES * 4);
    float* er2     = (float*)alloc((size_t)N_NODES * 4);
    int*   cntbuf  = (int*)alloc((size_t)2 * N_NODES * 4);  // cnt | fill
    int*   row_ptr = (int*)alloc((size_t)(N_NODES + 1) * 4);
    int*   csr_src = (int*)alloc((size_t)N_EDGES * 4);
    int*   cnt  = cntbuf;
    int*   fill = cntbuf + N_NODES;

    hipMemsetAsync(cntbuf, 0, (size_t)2 * N_NODES * 4, stream);

    dim3 b256(256);
    // CSR build
    hist_kernel<<<(N_EDGES + 255) / 256, b256, 0, stream>>>(dst, cnt);
    scan_kernel<<<1, 1024, 0, stream>>>(cnt, row_ptr);
    scatter_kernel<<<(N_EDGES + 255) / 256, b256, 0, stream>>>(src, dst, row_ptr, fill, csr_src);

    // layer 1
    dim3 g1((N_NODES + 63) / 64, 4);
    gemm1_kernel<<<g1, b256, 0, stream>>>(x, W1, feat1);
    lel1_kernel<<<(N_NODES + 3) / 4, b256, 0, stream>>>(feat1, al1, ar1, el1, er1);
    agg1_kernel<<<(N_NODES + 3) / 4, b256, 0, stream>>>(feat1, el1, er1, row_ptr, csr_src, b1, h1);

    // layer 2
    gemm2_kernel<<<(N_NODES + 15) / 16, b256, 0, stream>>>(h1, W2, feat2);
    lel2_kernel<<<(N_NODES + 255) / 256, b256, 0, stream>>>(feat2, al2, ar2, el2, er2);
    agg2_kernel<<<(N_NODES + 3) / 4, b256, 0, stream>>>(feat2, el2, er2, row_ptr, csr_src, b2, out);
}

// Round 2
// 371.407 us; speedup vs baseline: 1.5808x; 1.5808x over previous
//
#include <hip/hip_runtime.h>
#include <hip/hip_bf16.h>

#define N_NODES 50000
#define NP1     50001
#define N_EDGES 800000
#define NFEAT   256
#define NHID    64
#define HEADS   4
#define NCLASS  16
#define NEG_SLOPE 0.2f

typedef __attribute__((ext_vector_type(8))) short short8;
typedef __attribute__((ext_vector_type(4))) float floatx4;

__device__ __forceinline__ float b2f(unsigned short u) {
    return __uint_as_float(((unsigned int)u) << 16);
}
__device__ __forceinline__ unsigned short f2b(float f) {
    unsigned int x = __float_as_uint(f);
    unsigned int r = x + 0x7fffu + ((x >> 16) & 1u);
    return (unsigned short)(r >> 16);
}
__device__ __forceinline__ float leaky(float x) { return x > 0.f ? x : NEG_SLOPE * x; }

// ---------------- dtype conversion ----------------
__global__ void cvt_x_kernel(const float* __restrict__ x, unsigned short* __restrict__ xb) {
    int i = (blockIdx.x * 256 + threadIdx.x) * 8;
    float4 v0 = *(const float4*)&x[i];
    float4 v1 = *(const float4*)&x[i + 4];
    uint4 o;
    o.x = (unsigned int)f2b(v0.x) | ((unsigned int)f2b(v0.y) << 16);
    o.y = (unsigned int)f2b(v0.z) | ((unsigned int)f2b(v0.w) << 16);
    o.z = (unsigned int)f2b(v1.x) | ((unsigned int)f2b(v1.y) << 16);
    o.w = (unsigned int)f2b(v1.z) | ((unsigned int)f2b(v1.w) << 16);
    *(uint4*)&xb[i] = o;
}

// W1 [256 k][256 n] -> W1T bf16 [256 n][256 k]
__global__ void cvt_w1t_kernel(const float* __restrict__ W1, unsigned short* __restrict__ W1T) {
    int t = blockIdx.x * 256 + threadIdx.x;
    int n = t >> 8, k = t & 255;
    W1T[n * 256 + k] = f2b(W1[k * 256 + n]);
}

// ---------------- CSR build ----------------
__global__ void hist_kernel(const int* __restrict__ dst, int* __restrict__ cnt) {
    int e = blockIdx.x * blockDim.x + threadIdx.x;
    if (e < N_EDGES) atomicAdd(&cnt[dst[e]], 1);
}

// level-1 scan: 49 blocks x 256 thr, each thread 4 contiguous elems (block covers 1024)
__global__ __launch_bounds__(256) void scan1_kernel(const int* __restrict__ cnt,
                                                    int* __restrict__ partial,
                                                    int* __restrict__ bsum) {
    __shared__ int wsum[4];
    int t = threadIdx.x;
    int base = blockIdx.x * 1024 + t * 4;
    int v0 = (base + 0 < N_NODES) ? cnt[base + 0] : 0;
    int v1 = (base + 1 < N_NODES) ? cnt[base + 1] : 0;
    int v2 = (base + 2 < N_NODES) ? cnt[base + 2] : 0;
    int v3 = (base + 3 < N_NODES) ? cnt[base + 3] : 0;
    int s = v0 + v1 + v2 + v3;
    int lane = t & 63, w = t >> 6;
    int incl = s;
#pragma unroll
    for (int off = 1; off < 64; off <<= 1) {
        int x = __shfl_up(incl, off);
        if (lane >= off) incl += x;
    }
    if (lane == 63) wsum[w] = incl;
    __syncthreads();
    int woff = 0;
    for (int k = 0; k < w; ++k) woff += wsum[k];
    int excl = woff + incl - s;
    if (base + 0 < NP1) partial[base + 0] = excl;
    if (base + 1 < NP1) partial[base + 1] = excl + v0;
    if (base + 2 < NP1) partial[base + 2] = excl + v0 + v1;
    if (base + 3 < NP1) partial[base + 3] = excl + v0 + v1 + v2;
    if (t == 255) bsum[blockIdx.x] = woff + incl;
}

// level-2: 1 block, 64 threads, scan 49 block sums -> exclusive offsets
__global__ void scan2_kernel(const int* __restrict__ bsum, int* __restrict__ boff) {
    int t = threadIdx.x;
    int v = (t < 49) ? bsum[t] : 0;
    int incl = v;
#pragma unroll
    for (int off = 1; off < 64; off <<= 1) {
        int x = __shfl_up(incl, off);
        if (t >= off) incl += x;
    }
    if (t < 49) boff[t] = incl - v;
}

__global__ void scan3_kernel(const int* __restrict__ partial, const int* __restrict__ boff,
                             int* __restrict__ row_ptr) {
    int i = blockIdx.x * 256 + threadIdx.x;
    if (i < NP1) row_ptr[i] = partial[i] + boff[i >> 10];
}

__global__ void scatter_kernel(const int* __restrict__ src, const int* __restrict__ dst,
                               const int* __restrict__ row_ptr, int* __restrict__ fill,
                               int* __restrict__ csr_src) {
    int e = blockIdx.x * blockDim.x + threadIdx.x;
    if (e < N_EDGES) {
        int d = dst[e];
        int pos = row_ptr[d] + atomicAdd(&fill[d], 1);
        csr_src[pos] = src[e];
    }
}

// ---------------- GEMM1 (bf16 MFMA): feat1 = x @ W1, output bf16 ----------------
// A: xb [50000][256] bf16, BT: W1T [256 n][256 k] bf16, C: feat1 bf16 [50000][256]
// tile 128(M) x 64(N), BK=32; 4 waves: wave wm owns rows wm*32..+31 (2 m-frags x 4 n-frags)
__global__ __launch_bounds__(256) void gemm1_mfma_kernel(const unsigned short* __restrict__ A,
                                                         const unsigned short* __restrict__ BT,
                                                         unsigned short* __restrict__ C) {
    __shared__ unsigned short As[128][40];
    __shared__ unsigned short Bs[64][40];
    int t = threadIdx.x;
    int m0 = blockIdx.x * 128;
    int n0 = blockIdx.y * 64;
    int lane = t & 63, wm = t >> 6;
    int quad = lane >> 4, l16 = lane & 15;

    floatx4 acc[2][4];
#pragma unroll
    for (int i = 0; i < 2; ++i)
#pragma unroll
        for (int j = 0; j < 4; ++j) acc[i][j] = (floatx4){0.f, 0.f, 0.f, 0.f};

    for (int k0 = 0; k0 < 256; k0 += 32) {
        // stage A: 128 rows x 32 bf16 (2 x 16B chunks per thread)
#pragma unroll
        for (int c = 0; c < 2; ++c) {
            int cid = t + c * 256;
            int row = cid >> 2, off = (cid & 3) * 8;
            int grow = m0 + row;
            float4 v = make_float4(0.f, 0.f, 0.f, 0.f);
            if (grow < N_NODES) v = *(const float4*)(A + (size_t)grow * 256 + k0 + off);
            *(float4*)(&As[row][off]) = v;
        }
        // stage B^T: 64 rows x 32 bf16 (1 x 16B chunk per thread)
        {
            int row = t >> 2, off = (t & 3) * 8;
            *(float4*)(&Bs[row][off]) = *(const float4*)(BT + (size_t)(n0 + row) * 256 + k0 + off);
        }
        __syncthreads();

        short8 a0 = *(const short8*)(&As[wm * 32 + l16][quad * 8]);
        short8 a1 = *(const short8*)(&As[wm * 32 + 16 + l16][quad * 8]);
#pragma unroll
        for (int nf = 0; nf < 4; ++nf) {
            short8 b = *(const short8*)(&Bs[nf * 16 + l16][quad * 8]);
            acc[0][nf] = __builtin_amdgcn_mfma_f32_16x16x32_bf16(a0, b, acc[0][nf], 0, 0, 0);
            acc[1][nf] = __builtin_amdgcn_mfma_f32_16x16x32_bf16(a1, b, acc[1][nf], 0, 0, 0);
        }
        __syncthreads();
    }
    // epilogue: D row=(quad*4+reg), col=l16
#pragma unroll
    for (int mf = 0; mf < 2; ++mf) {
#pragma unroll
        for (int r = 0; r < 4; ++r) {
            int row = m0 + wm * 32 + mf * 16 + quad * 4 + r;
            if (row < N_NODES) {
#pragma unroll
                for (int nf = 0; nf < 4; ++nf) {
                    int col = n0 + nf * 16 + l16;
                    C[(size_t)row * 256 + col] = f2b(acc[mf][nf][r]);
                }
            }
        }
    }
}

// ---------------- el1/er1 from bf16 feat1 ----------------
__global__ void lel1_kernel(const unsigned short* __restrict__ feat1,
                            const float* __restrict__ al, const float* __restrict__ ar,
                            float* __restrict__ el, float* __restrict__ er) {
    int wave = threadIdx.x >> 6, lane = threadIdx.x & 63;
    int n = blockIdx.x * 4 + wave;
    if (n >= N_NODES) return;
    ushort4 u = *(const ushort4*)&feat1[(size_t)n * 256 + lane * 4];
    float f0 = b2f(u.x), f1 = b2f(u.y), f2 = b2f(u.z), f3 = b2f(u.w);
    float4 a = *(const float4*)&al[lane * 4];
    float4 r = *(const float4*)&ar[lane * 4];
    float pl = f0 * a.x + f1 * a.y + f2 * a.z + f3 * a.w;
    float pr = f0 * r.x + f1 * r.y + f2 * r.z + f3 * r.w;
#pragma unroll
    for (int off = 1; off < 16; off <<= 1) {
        pl += __shfl_xor(pl, off);
        pr += __shfl_xor(pr, off);
    }
    if ((lane & 15) == 0) {
        el[n * 4 + (lane >> 4)] = pl;
        er[n * 4 + (lane >> 4)] = pr;
    }
}

// ---------------- layer-1 aggregation: one wave per dst node, bf16 gather ----------------
__global__ void agg1_kernel(const unsigned short* __restrict__ feat1,
                            const float* __restrict__ el, const float* __restrict__ er,
                            const int* __restrict__ row_ptr, const int* __restrict__ csr_src,
                            const float* __restrict__ b1, float* __restrict__ h1) {
    int wave = threadIdx.x >> 6, lane = threadIdx.x & 63;
    int n = blockIdx.x * 4 + wave;
    if (n >= N_NODES) return;
    int start = row_ptr[n], end = row_ptr[n + 1];
    float4 er4 = *(const float4*)&er[n * 4];

    // pass 1: per-head max
    float4 m = make_float4(-1e30f, -1e30f, -1e30f, -1e30f);
    for (int i = start + lane; i < end; i += 64) {
        int s = csr_src[i];
        float4 el4 = *(const float4*)&el[s * 4];
        m.x = fmaxf(m.x, leaky(el4.x + er4.x));
        m.y = fmaxf(m.y, leaky(el4.y + er4.y));
        m.z = fmaxf(m.z, leaky(el4.z + er4.z));
        m.w = fmaxf(m.w, leaky(el4.w + er4.w));
    }
#pragma unroll
    for (int off = 32; off; off >>= 1) {
        m.x = fmaxf(m.x, __shfl_xor(m.x, off));
        m.y = fmaxf(m.y, __shfl_xor(m.y, off));
        m.z = fmaxf(m.z, __shfl_xor(m.z, off));
        m.w = fmaxf(m.w, __shfl_xor(m.w, off));
    }
    int h = lane >> 4;
    float m_h  = (h == 0) ? m.x : (h == 1) ? m.y : (h == 2) ? m.z : m.w;
    float er_h = (h == 0) ? er4.x : (h == 1) ? er4.y : (h == 2) ? er4.z : er4.w;

    // pass 2: accumulate feat[src]*exp(e-m) and denom (2-way unrolled)
    float4 acc = make_float4(0.f, 0.f, 0.f, 0.f);
    float denom = 0.f;
    int i = start;
    for (; i + 1 < end; i += 2) {
        int s0 = csr_src[i], s1 = csr_src[i + 1];
        float ex0 = __expf(leaky(el[s0 * 4 + h] + er_h) - m_h);
        float ex1 = __expf(leaky(el[s1 * 4 + h] + er_h) - m_h);
        ushort4 u0 = *(const ushort4*)&feat1[(size_t)s0 * 256 + lane * 4];
        ushort4 u1 = *(const ushort4*)&feat1[(size_t)s1 * 256 + lane * 4];
        denom += ex0 + ex1;
        acc.x += b2f(u0.x) * ex0 + b2f(u1.x) * ex1;
        acc.y += b2f(u0.y) * ex0 + b2f(u1.y) * ex1;
        acc.z += b2f(u0.z) * ex0 + b2f(u1.z) * ex1;
        acc.w += b2f(u0.w) * ex0 + b2f(u1.w) * ex1;
    }
    for (; i < end; ++i) {
        int s = csr_src[i];
        float ex = __expf(leaky(el[s * 4 + h] + er_h) - m_h);
        ushort4 u = *(const ushort4*)&feat1[(size_t)s * 256 + lane * 4];
        denom += ex;
        acc.x += b2f(u.x) * ex;
        acc.y += b2f(u.y) * ex;
        acc.z += b2f(u.z) * ex;
        acc.w += b2f(u.w) * ex;
    }
    float inv = (end > start) ? 1.f / denom : 0.f;
    float4 b4 = *(const float4*)&b1[lane * 4];
    float4 o;
    o.x = acc.x * inv + b4.x;
    o.y = acc.y * inv + b4.y;
    o.z = acc.z * inv + b4.z;
    o.w = acc.w * inv + b4.w;
    o.x = o.x > 0.f ? o.x : __expf(o.x) - 1.f;
    o.y = o.y > 0.f ? o.y : __expf(o.y) - 1.f;
    o.z = o.z > 0.f ? o.z : __expf(o.z) - 1.f;
    o.w = o.w > 0.f ? o.w : __expf(o.w) - 1.f;
    *(float4*)&h1[(size_t)n * 256 + lane * 4] = o;
}

// ---------------- GEMM2 + fused el2/er2 ----------------
__global__ __launch_bounds__(256) void gemm2_kernel(const float* __restrict__ h1,
                                                    const float* __restrict__ W2,
                                                    const float* __restrict__ al2,
                                                    const float* __restrict__ ar2,
                                                    float* __restrict__ feat2,
                                                    float* __restrict__ el2,
                                                    float* __restrict__ er2) {
    __shared__ float Ws[4096];
    __shared__ float As[16][264];
    int t = threadIdx.x;
    int row0 = blockIdx.x * 16;
#pragma unroll
    for (int i = 0; i < 16; ++i) Ws[t + i * 256] = W2[t + i * 256];
    int r = t >> 4, kb = (t & 15) * 16;
    int row = row0 + r;
    if (row < N_NODES) {
#pragma unroll
        for (int j = 0; j < 16; j += 4)
            *(float4*)&As[r][kb + j] = *(const float4*)&h1[(size_t)row * 256 + kb + j];
    } else {
#pragma unroll
        for (int j = 0; j < 16; j += 4)
            *(float4*)&As[r][kb + j] = make_float4(0.f, 0.f, 0.f, 0.f);
    }
    __syncthreads();
    int c = t & 15;
    float acc = 0.f;
#pragma unroll 8
    for (int k = 0; k < 256; ++k) acc += As[r][k] * Ws[k * 16 + c];
    // fused attention dots: reduce across the 16 class lanes
    float pl = acc * al2[c], pr = acc * ar2[c];
#pragma unroll
    for (int off = 1; off < 16; off <<= 1) {
        pl += __shfl_xor(pl, off);
        pr += __shfl_xor(pr, off);
    }
    if (row < N_NODES) {
        feat2[row * 16 + c] = acc;
        if (c == 0) { el2[row] = pl; er2[row] = pr; }
    }
}

// ---------------- layer-2 aggregation + log_softmax (4 edges/iter) ----------------
__global__ void agg2_kernel(const float* __restrict__ feat2, const float* __restrict__ el2,
                            const float* __restrict__ er2, const int* __restrict__ row_ptr,
                            const int* __restrict__ csr_src, const float* __restrict__ b2,
                            float* __restrict__ out) {
    int wave = threadIdx.x >> 6, lane = threadIdx.x & 63;
    int n = blockIdx.x * 4 + wave;
    if (n >= N_NODES) return;
    int start = row_ptr[n], end = row_ptr[n + 1];
    float ern = er2[n];
    float m = -1e30f;
    for (int i = start + lane; i < end; i += 64) {
        int s = csr_src[i];
        m = fmaxf(m, leaky(el2[s] + ern));
    }
#pragma unroll
    for (int off = 32; off; off >>= 1) m = fmaxf(m, __shfl_xor(m, off));
    int eo = lane >> 4, c = lane & 15;
    float acc = 0.f, denom = 0.f;
    for (int i = start; i < end; i += 4) {
        int ii = i + eo;
        if (ii < end) {
            int s = csr_src[ii];
            float ex = __expf(leaky(el2[s] + ern) - m);
            denom += ex;
            acc += feat2[s * 16 + c] * ex;
        }
    }
    // combine the 4 edge-groups
    acc += __shfl_xor(acc, 16);
    acc += __shfl_xor(acc, 32);
    denom += __shfl_xor(denom, 16);
    denom += __shfl_xor(denom, 32);
    float v = ((end > start) ? acc / denom : 0.f) + b2[c];
    // log_softmax over 16 classes (within each 16-lane group)
    float mx = v;
#pragma unroll
    for (int off = 1; off < 16; off <<= 1) mx = fmaxf(mx, __shfl_xor(mx, off));
    float ex2 = __expf(v - mx);
    float s2 = ex2;
#pragma unroll
    for (int off = 1; off < 16; off <<= 1) s2 += __shfl_xor(s2, off);
    float res = v - mx - logf(s2);
    if (lane < 16) out[n * 16 + lane] = res;
}

// ---------------- launch ----------------
extern "C" void kernel_launch(void* const* d_in, const int* in_sizes, int n_in,
                              void* d_out, int out_size, void* d_ws, size_t ws_size,
                              hipStream_t stream) {
    const float* x   = (const float*)d_in[0];
    const int*   src = (const int*)d_in[1];
    const int*   dst = (const int*)d_in[2];
    const float* W1  = (const float*)d_in[3];
    const float* al1 = (const float*)d_in[4];
    const float* ar1 = (const float*)d_in[5];
    const float* b1  = (const float*)d_in[6];
    const float* W2  = (const float*)d_in[7];
    const float* al2 = (const float*)d_in[8];
    const float* ar2 = (const float*)d_in[9];
    const float* b2  = (const float*)d_in[10];
    float* out = (float*)d_out;

    char* ws = (char*)d_ws;
    size_t off = 0;
    auto alloc = [&](size_t bytes) -> void* {
        void* p = ws + off;
        off += (bytes + 255) & ~(size_t)255;
        return p;
    };
    unsigned short* xb     = (unsigned short*)alloc((size_t)N_NODES * 256 * 2);
    unsigned short* W1T    = (unsigned short*)alloc((size_t)256 * 256 * 2);
    unsigned short* feat1  = (unsigned short*)alloc((size_t)N_NODES * 256 * 2);
    float* h1      = (float*)alloc((size_t)N_NODES * 256 * 4);
    float* feat2   = (float*)alloc((size_t)N_NODES * 16 * 4);
    float* el1     = (float*)alloc((size_t)N_NODES * 4 * 4);
    float* er1     = (float*)alloc((size_t)N_NODES * 4 * 4);
    float* el2     = (float*)alloc((size_t)N_NODES * 4);
    float* er2     = (float*)alloc((size_t)N_NODES * 4);
    int*   cntbuf  = (int*)alloc((size_t)2 * N_NODES * 4);  // cnt | fill
    int*   row_ptr = (int*)alloc((size_t)NP1 * 4);
    int*   partial = (int*)alloc((size_t)NP1 * 4);
    int*   bsum    = (int*)alloc((size_t)64 * 4);
    int*   boff    = (int*)alloc((size_t)64 * 4);
    int*   csr_src = (int*)alloc((size_t)N_EDGES * 4);
    int*   cnt  = cntbuf;
    int*   fill = cntbuf + N_NODES;

    hipMemsetAsync(cntbuf, 0, (size_t)2 * N_NODES * 4, stream);

    dim3 b256(256);
    // conversions
    cvt_x_kernel<<<6250, b256, 0, stream>>>(x, xb);
    cvt_w1t_kernel<<<256, b256, 0, stream>>>(W1, W1T);
    // CSR build
    hist_kernel<<<(N_EDGES + 255) / 256, b256, 0, stream>>>(dst, cnt);
    scan1_kernel<<<49, b256, 0, stream>>>(cnt, partial, bsum);
    scan2_kernel<<<1, 64, 0, stream>>>(bsum, boff);
    scan3_kernel<<<(NP1 + 255) / 256, b256, 0, stream>>>(partial, boff, row_ptr);
    scatter_kernel<<<(N_EDGES + 255) / 256, b256, 0, stream>>>(src, dst, row_ptr, fill, csr_src);

    // layer 1
    dim3 g1((N_NODES + 127) / 128, 4);
    gemm1_mfma_kernel<<<g1, b256, 0, stream>>>(xb, W1T, feat1);
    lel1_kernel<<<(N_NODES + 3) / 4, b256, 0, stream>>>(feat1, al1, ar1, el1, er1);
    agg1_kernel<<<(N_NODES + 3) / 4, b256, 0, stream>>>(feat1, el1, er1, row_ptr, csr_src, b1, h1);

    // layer 2
    gemm2_kernel<<<(N_NODES + 15) / 16, b256, 0, stream>>>(h1, W2, al2, ar2, feat2, el2, er2);
    agg2_kernel<<<(N_NODES + 3) / 4, b256, 0, stream>>>(feat2, el2, er2, row_ptr, csr_src, b2, out);
}

// Round 3
// 327.964 us; speedup vs baseline: 1.7902x; 1.1325x over previous
//
#include <hip/hip_runtime.h>
#include <hip/hip_bf16.h>

#define N_NODES 50000
#define NP1     50001
#define N_EDGES 800000
#define NFEAT   256
#define NHID    64
#define HEADS   4
#define NCLASS  16
#define NEG_SLOPE 0.2f

typedef __attribute__((ext_vector_type(8))) short short8;
typedef __attribute__((ext_vector_type(4))) float floatx4;

__device__ __forceinline__ float b2f(unsigned short u) {
    return __uint_as_float(((unsigned int)u) << 16);
}
__device__ __forceinline__ float blo(unsigned int u) { return __uint_as_float(u << 16); }
__device__ __forceinline__ float bhi(unsigned int u) { return __uint_as_float(u & 0xffff0000u); }
__device__ __forceinline__ unsigned short f2b(float f) {
    unsigned int x = __float_as_uint(f);
    unsigned int r = x + 0x7fffu + ((x >> 16) & 1u);
    return (unsigned short)(r >> 16);
}
__device__ __forceinline__ unsigned int pack2(float a, float b) {
    return (unsigned int)f2b(a) | ((unsigned int)f2b(b) << 16);
}
__device__ __forceinline__ float leaky(float x) { return fmaxf(x, NEG_SLOPE * x); }

// ---------------- weight conversions ----------------
// W1 [256 k][256 n] -> W1T bf16 [256 n][256 k]
__global__ void cvt_w1t_kernel(const float* __restrict__ W1, unsigned short* __restrict__ W1T) {
    int t = blockIdx.x * 256 + threadIdx.x;
    int n = t >> 8, k = t & 255;
    W1T[n * 256 + k] = f2b(W1[k * 256 + n]);
}
// W2 [256 k][16 n] -> W2T bf16 [16 n][256 k]
__global__ void cvt_w2t_kernel(const float* __restrict__ W2, unsigned short* __restrict__ W2T) {
    int t = threadIdx.x;
    int n = t >> 4, k0 = (t & 15) * 16;
#pragma unroll
    for (int j = 0; j < 16; ++j)
        W2T[n * 256 + k0 + j] = f2b(W2[(k0 + j) * 16 + n]);
}

// ---------------- CSR build ----------------
__global__ void hist_kernel(const int* __restrict__ dst, int* __restrict__ cnt) {
    int e = blockIdx.x * blockDim.x + threadIdx.x;
    if (e < N_EDGES) atomicAdd(&cnt[dst[e]], 1);
}

__global__ __launch_bounds__(256) void scan1_kernel(const int* __restrict__ cnt,
                                                    int* __restrict__ partial,
                                                    int* __restrict__ bsum) {
    __shared__ int wsum[4];
    int t = threadIdx.x;
    int base = blockIdx.x * 1024 + t * 4;
    int v0 = (base + 0 < N_NODES) ? cnt[base + 0] : 0;
    int v1 = (base + 1 < N_NODES) ? cnt[base + 1] : 0;
    int v2 = (base + 2 < N_NODES) ? cnt[base + 2] : 0;
    int v3 = (base + 3 < N_NODES) ? cnt[base + 3] : 0;
    int s = v0 + v1 + v2 + v3;
    int lane = t & 63, w = t >> 6;
    int incl = s;
#pragma unroll
    for (int off = 1; off < 64; off <<= 1) {
        int x = __shfl_up(incl, off);
        if (lane >= off) incl += x;
    }
    if (lane == 63) wsum[w] = incl;
    __syncthreads();
    int woff = 0;
    for (int k = 0; k < w; ++k) woff += wsum[k];
    int excl = woff + incl - s;
    if (base + 0 < NP1) partial[base + 0] = excl;
    if (base + 1 < NP1) partial[base + 1] = excl + v0;
    if (base + 2 < NP1) partial[base + 2] = excl + v0 + v1;
    if (base + 3 < NP1) partial[base + 3] = excl + v0 + v1 + v2;
    if (t == 255) bsum[blockIdx.x] = woff + incl;
}

__global__ void scan2_kernel(const int* __restrict__ bsum, int* __restrict__ boff) {
    int t = threadIdx.x;
    int v = (t < 49) ? bsum[t] : 0;
    int incl = v;
#pragma unroll
    for (int off = 1; off < 64; off <<= 1) {
        int x = __shfl_up(incl, off);
        if (t >= off) incl += x;
    }
    if (t < 49) boff[t] = incl - v;
}

__global__ void scan3_kernel(const int* __restrict__ partial, const int* __restrict__ boff,
                             int* __restrict__ row_ptr, int* __restrict__ fill) {
    int i = blockIdx.x * 256 + threadIdx.x;
    if (i < NP1) {
        int v = partial[i] + boff[i >> 10];
        row_ptr[i] = v;
        if (i < N_NODES) fill[i] = v;
    }
}

__global__ void scatter_kernel(const int* __restrict__ src, const int* __restrict__ dst,
                               int* __restrict__ fill, int* __restrict__ csr_src) {
    int e = blockIdx.x * blockDim.x + threadIdx.x;
    if (e < N_EDGES) {
        int pos = atomicAdd(&fill[dst[e]], 1);
        csr_src[pos] = src[e];
    }
}

// ---------------- GEMM1 (bf16 MFMA): feat1 = x @ W1, fused el1/er1 ----------------
// x fp32 [50000][256] (converted to bf16 during staging), W1T bf16 [256 n][256 k]
// tile 128(M) x 256(N), BK=32; 4 waves: wave wm owns rows wm*32..+31 (2 m x 16 n frags)
__global__ __launch_bounds__(256, 2) void gemm1_mfma_kernel(
        const float* __restrict__ X, const unsigned short* __restrict__ BT,
        unsigned short* __restrict__ C, const float* __restrict__ al1,
        const float* __restrict__ ar1, float* __restrict__ el, float* __restrict__ er) {
    __shared__ unsigned short As[128][40];
    __shared__ unsigned short Bs[256][40];
    int t = threadIdx.x;
    int m0 = blockIdx.x * 128;
    int lane = t & 63, wm = t >> 6;
    int quad = lane >> 4, l16 = lane & 15;

    floatx4 acc[2][16];
#pragma unroll
    for (int i = 0; i < 2; ++i)
#pragma unroll
        for (int j = 0; j < 16; ++j) acc[i][j] = (floatx4){0.f, 0.f, 0.f, 0.f};

    int arow = t >> 1, ak = (t & 1) * 16;
    int grow = m0 + arow;
    const float* xrow = X + (size_t)grow * 256 + ak;
    const unsigned short* brow = BT + (size_t)t * 256;

    for (int k0 = 0; k0 < 256; k0 += 32) {
        // stage A: fp32 -> bf16, 16 elems/thread
        float4 v0 = make_float4(0.f, 0.f, 0.f, 0.f), v1 = v0, v2 = v0, v3 = v0;
        if (grow < N_NODES) {
            v0 = *(const float4*)(xrow + k0 + 0);
            v1 = *(const float4*)(xrow + k0 + 4);
            v2 = *(const float4*)(xrow + k0 + 8);
            v3 = *(const float4*)(xrow + k0 + 12);
        }
        uint4 p0, p1;
        p0.x = pack2(v0.x, v0.y); p0.y = pack2(v0.z, v0.w);
        p0.z = pack2(v1.x, v1.y); p0.w = pack2(v1.z, v1.w);
        p1.x = pack2(v2.x, v2.y); p1.y = pack2(v2.z, v2.w);
        p1.z = pack2(v3.x, v3.y); p1.w = pack2(v3.z, v3.w);
        *(uint4*)&As[arow][ak] = p0;
        *(uint4*)&As[arow][ak + 8] = p1;
        // stage B^T: row t, 32 k bf16 = 64B
        uint4 b0 = *(const uint4*)(brow + k0);
        uint4 b1v = *(const uint4*)(brow + k0 + 8);
        uint4 b2v = *(const uint4*)(brow + k0 + 16);
        uint4 b3v = *(const uint4*)(brow + k0 + 24);
        *(uint4*)&Bs[t][0] = b0;
        *(uint4*)&Bs[t][8] = b1v;
        *(uint4*)&Bs[t][16] = b2v;
        *(uint4*)&Bs[t][24] = b3v;
        __syncthreads();

        short8 a0 = *(const short8*)(&As[wm * 32 + l16][quad * 8]);
        short8 a1 = *(const short8*)(&As[wm * 32 + 16 + l16][quad * 8]);
#pragma unroll
        for (int nf = 0; nf < 16; ++nf) {
            short8 b = *(const short8*)(&Bs[nf * 16 + l16][quad * 8]);
            acc[0][nf] = __builtin_amdgcn_mfma_f32_16x16x32_bf16(a0, b, acc[0][nf], 0, 0, 0);
            acc[1][nf] = __builtin_amdgcn_mfma_f32_16x16x32_bf16(a1, b, acc[1][nf], 0, 0, 0);
        }
        __syncthreads();
    }

    // per-lane attn vectors for fused el/er
    float alv[16], arv[16];
#pragma unroll
    for (int nf = 0; nf < 16; ++nf) {
        alv[nf] = al1[nf * 16 + l16];
        arv[nf] = ar1[nf * 16 + l16];
    }

#pragma unroll
    for (int mf = 0; mf < 2; ++mf) {
#pragma unroll
        for (int r = 0; r < 4; ++r) {
            int row = m0 + wm * 32 + mf * 16 + quad * 4 + r;
            bool ok = row < N_NODES;
            float pl[4] = {0.f, 0.f, 0.f, 0.f};
            float pr[4] = {0.f, 0.f, 0.f, 0.f};
#pragma unroll
            for (int nf = 0; nf < 16; ++nf) {
                float v = acc[mf][nf][r];
                if (ok) C[(size_t)row * 256 + nf * 16 + l16] = f2b(v);
                pl[nf >> 2] += v * alv[nf];
                pr[nf >> 2] += v * arv[nf];
            }
#pragma unroll
            for (int h = 0; h < 4; ++h) {
#pragma unroll
                for (int off = 1; off < 16; off <<= 1) {
                    pl[h] += __shfl_xor(pl[h], off);
                    pr[h] += __shfl_xor(pr[h], off);
                }
            }
            if (ok && l16 < 4) {
                float vl = (l16 == 0) ? pl[0] : (l16 == 1) ? pl[1] : (l16 == 2) ? pl[2] : pl[3];
                float vr = (l16 == 0) ? pr[0] : (l16 == 1) ? pr[1] : (l16 == 2) ? pr[2] : pr[3];
                el[row * 4 + l16] = vl;
                er[row * 4 + l16] = vr;
            }
        }
    }
}

// ---------------- layer-1 aggregation: one wave per dst, 2 edges/iter, no max pass ----------------
__global__ void agg1_kernel(const unsigned short* __restrict__ feat1,
                            const float* __restrict__ el, const float* __restrict__ er,
                            const int* __restrict__ row_ptr, const int* __restrict__ csr_src,
                            const float* __restrict__ b1, unsigned short* __restrict__ h1b) {
    int wave = threadIdx.x >> 6, lane = threadIdx.x & 63;
    int n = blockIdx.x * 4 + wave;
    if (n >= N_NODES) return;
    int start = row_ptr[n], end = row_ptr[n + 1];
    int l32 = lane & 31, half = lane >> 5, h = l32 >> 3;
    float er_h = er[n * 4 + h];

    float acc[8] = {0.f, 0.f, 0.f, 0.f, 0.f, 0.f, 0.f, 0.f};
    float denom = 0.f;
    for (int i = start + half; i < end; i += 2) {
        int s = csr_src[i];
        float ex = __expf(leaky(el[s * 4 + h] + er_h));
        uint4 u = *(const uint4*)(feat1 + (size_t)s * 256 + l32 * 8);
        denom += ex;
        acc[0] = fmaf(blo(u.x), ex, acc[0]);
        acc[1] = fmaf(bhi(u.x), ex, acc[1]);
        acc[2] = fmaf(blo(u.y), ex, acc[2]);
        acc[3] = fmaf(bhi(u.y), ex, acc[3]);
        acc[4] = fmaf(blo(u.z), ex, acc[4]);
        acc[5] = fmaf(bhi(u.z), ex, acc[5]);
        acc[6] = fmaf(blo(u.w), ex, acc[6]);
        acc[7] = fmaf(bhi(u.w), ex, acc[7]);
    }
    denom += __shfl_xor(denom, 32);
#pragma unroll
    for (int j = 0; j < 8; ++j) acc[j] += __shfl_xor(acc[j], 32);

    if (half == 0) {
        float inv = (end > start) ? 1.f / denom : 0.f;
        float4 bA = *(const float4*)&b1[l32 * 8];
        float4 bB = *(const float4*)&b1[l32 * 8 + 4];
        float o[8];
        o[0] = fmaf(acc[0], inv, bA.x);
        o[1] = fmaf(acc[1], inv, bA.y);
        o[2] = fmaf(acc[2], inv, bA.z);
        o[3] = fmaf(acc[3], inv, bA.w);
        o[4] = fmaf(acc[4], inv, bB.x);
        o[5] = fmaf(acc[5], inv, bB.y);
        o[6] = fmaf(acc[6], inv, bB.z);
        o[7] = fmaf(acc[7], inv, bB.w);
#pragma unroll
        for (int j = 0; j < 8; ++j) o[j] = o[j] > 0.f ? o[j] : __expf(o[j]) - 1.f;
        uint4 p;
        p.x = pack2(o[0], o[1]);
        p.y = pack2(o[2], o[3]);
        p.z = pack2(o[4], o[5]);
        p.w = pack2(o[6], o[7]);
        *(uint4*)(h1b + (size_t)n * 256 + l32 * 8) = p;
    }
}

// ---------------- GEMM2 (bf16 MFMA, no LDS) + fused el2/er2 ----------------
__global__ __launch_bounds__(256) void gemm2_mfma_kernel(
        const unsigned short* __restrict__ h1b, const unsigned short* __restrict__ W2T,
        const float* __restrict__ al2, const float* __restrict__ ar2,
        float* __restrict__ feat2, float* __restrict__ el2, float* __restrict__ er2) {
    int wave = threadIdx.x >> 6, lane = threadIdx.x & 63;
    int l16 = lane & 15, quad = lane >> 4;
    int row0 = (blockIdx.x * 4 + wave) * 16;
    if (row0 >= N_NODES) return;
    floatx4 acc = (floatx4){0.f, 0.f, 0.f, 0.f};
    const unsigned short* arow = h1b + (size_t)(row0 + l16) * 256 + quad * 8;
    const unsigned short* brow = W2T + (size_t)l16 * 256 + quad * 8;
#pragma unroll
    for (int k0 = 0; k0 < 256; k0 += 32) {
        short8 a = *(const short8*)(arow + k0);
        short8 b = *(const short8*)(brow + k0);
        acc = __builtin_amdgcn_mfma_f32_16x16x32_bf16(a, b, acc, 0, 0, 0);
    }
    float a2 = al2[l16], r2 = ar2[l16];
#pragma unroll
    for (int r = 0; r < 4; ++r) {
        int row = row0 + quad * 4 + r;
        float v = acc[r];
        feat2[row * 16 + l16] = v;
        float pl = v * a2, pr = v * r2;
#pragma unroll
        for (int off = 1; off < 16; off <<= 1) {
            pl += __shfl_xor(pl, off);
            pr += __shfl_xor(pr, off);
        }
        if (l16 == 0) {
            el2[row] = pl;
            er2[row] = pr;
        }
    }
}

// ---------------- layer-2 aggregation + log_softmax, no max pass ----------------
__global__ void agg2_kernel(const float* __restrict__ feat2, const float* __restrict__ el2,
                            const float* __restrict__ er2, const int* __restrict__ row_ptr,
                            const int* __restrict__ csr_src, const float* __restrict__ b2,
                            float* __restrict__ out) {
    int wave = threadIdx.x >> 6, lane = threadIdx.x & 63;
    int n = blockIdx.x * 4 + wave;
    if (n >= N_NODES) return;
    int start = row_ptr[n], end = row_ptr[n + 1];
    float ern = er2[n];
    int eo = lane >> 4, c = lane & 15;
    float acc = 0.f, denom = 0.f;
    for (int i = start + eo; i < end; i += 4) {
        int s = csr_src[i];
        float ex = __expf(leaky(el2[s] + ern));
        denom += ex;
        acc = fmaf(feat2[s * 16 + c], ex, acc);
    }
    acc += __shfl_xor(acc, 16);
    acc += __shfl_xor(acc, 32);
    denom += __shfl_xor(denom, 16);
    denom += __shfl_xor(denom, 32);
    float v = ((end > start) ? acc / denom : 0.f) + b2[c];
    float mx = v;
#pragma unroll
    for (int off = 1; off < 16; off <<= 1) mx = fmaxf(mx, __shfl_xor(mx, off));
    float ex2 = __expf(v - mx);
    float s2 = ex2;
#pragma unroll
    for (int off = 1; off < 16; off <<= 1) s2 += __shfl_xor(s2, off);
    float res = v - mx - logf(s2);
    if (lane < 16) out[n * 16 + lane] = res;
}

// ---------------- launch ----------------
extern "C" void kernel_launch(void* const* d_in, const int* in_sizes, int n_in,
                              void* d_out, int out_size, void* d_ws, size_t ws_size,
                              hipStream_t stream) {
    const float* x   = (const float*)d_in[0];
    const int*   src = (const int*)d_in[1];
    const int*   dst = (const int*)d_in[2];
    const float* W1  = (const float*)d_in[3];
    const float* al1 = (const float*)d_in[4];
    const float* ar1 = (const float*)d_in[5];
    const float* b1  = (const float*)d_in[6];
    const float* W2  = (const float*)d_in[7];
    const float* al2 = (const float*)d_in[8];
    const float* ar2 = (const float*)d_in[9];
    const float* b2  = (const float*)d_in[10];
    float* out = (float*)d_out;

    char* ws = (char*)d_ws;
    size_t off = 0;
    auto alloc = [&](size_t bytes) -> void* {
        void* p = ws + off;
        off += (bytes + 255) & ~(size_t)255;
        return p;
    };
    unsigned short* W1T   = (unsigned short*)alloc((size_t)256 * 256 * 2);
    unsigned short* W2T   = (unsigned short*)alloc((size_t)16 * 256 * 2);
    unsigned short* feat1 = (unsigned short*)alloc((size_t)N_NODES * 256 * 2);
    unsigned short* h1b   = (unsigned short*)alloc((size_t)N_NODES * 256 * 2);
    float* feat2   = (float*)alloc((size_t)N_NODES * 16 * 4);
    float* el1     = (float*)alloc((size_t)N_NODES * 4 * 4);
    float* er1     = (float*)alloc((size_t)N_NODES * 4 * 4);
    float* el2     = (float*)alloc((size_t)N_NODES * 4);
    float* er2     = (float*)alloc((size_t)N_NODES * 4);
    int*   cnt     = (int*)alloc((size_t)N_NODES * 4);
    int*   fill    = (int*)alloc((size_t)N_NODES * 4);
    int*   row_ptr = (int*)alloc((size_t)NP1 * 4);
    int*   partial = (int*)alloc((size_t)NP1 * 4);
    int*   bsum    = (int*)alloc((size_t)64 * 4);
    int*   boff    = (int*)alloc((size_t)64 * 4);
    int*   csr_src = (int*)alloc((size_t)N_EDGES * 4);

    hipMemsetAsync(cnt, 0, (size_t)N_NODES * 4, stream);

    dim3 b256(256);
    cvt_w1t_kernel<<<256, b256, 0, stream>>>(W1, W1T);
    cvt_w2t_kernel<<<1, b256, 0, stream>>>(W2, W2T);
    // CSR build
    hist_kernel<<<(N_EDGES + 255) / 256, b256, 0, stream>>>(dst, cnt);
    scan1_kernel<<<49, b256, 0, stream>>>(cnt, partial, bsum);
    scan2_kernel<<<1, 64, 0, stream>>>(bsum, boff);
    scan3_kernel<<<(NP1 + 255) / 256, b256, 0, stream>>>(partial, boff, row_ptr, fill);
    scatter_kernel<<<(N_EDGES + 255) / 256, b256, 0, stream>>>(src, dst, fill, csr_src);

    // layer 1
    gemm1_mfma_kernel<<<(N_NODES + 127) / 128, b256, 0, stream>>>(x, W1T, feat1, al1, ar1, el1, er1);
    agg1_kernel<<<(N_NODES + 3) / 4, b256, 0, stream>>>(feat1, el1, er1, row_ptr, csr_src, b1, h1b);

    // layer 2
    gemm2_mfma_kernel<<<(N_NODES + 63) / 64, b256, 0, stream>>>(h1b, W2T, al2, ar2, feat2, el2, er2);
    agg2_kernel<<<(N_NODES + 3) / 4, b256, 0, stream>>>(feat2, el2, er2, row_ptr, csr_src, b2, out);
}